// Round 9
// baseline (388.440 us; speedup 1.0000x reference)
//
#include <hip/hip_runtime.h>
#include <cstdint>
#include <cstddef>

// ---------------------------------------------------------------------------
// EdgeDecoder, swapped-operand formulation, AGPR accumulators + pipelined gather.
//   Layer0: D0 = W0^T (A-frag, LDS) @ X^T (B-frag, gathered)   [C: lane=edge col]
//   transform: ELU + cvt_pkrtz + permlane32/16_swap -> layer-1 B-frags (no LDS)
//   Layer1: D1 = W1^T (A-frag, LDS) @ H0^T (B-frag, registers)
//   Layer2: per-lane dot (32 ch) + xor16/xor32 reduce + coalesced store
// Round-7 (verified, 268 us): AGPR accs, pipelined gather, bias via C-init
// copies. Round-8 FAILED correctness (absmax 0.082): bundled mfma C!=D init
// ("=a", no early-clobber -> output may alias an input), exp2-ELU, fused
// transform. Round-9 = round-7 verbatim EXCEPT the bias-init elimination done
// safely:
//   * mfma_init uses "=&a" EARLY-CLOBBER: output disjoint from all inputs.
//   * b0A/b1A pinned to AGPRs once via asm("":"+a") and consumed only by the
//     MFMA C operand -> kills 128 v_accvgpr_write init moves/tile.
//   * single acc[2][8] reused across layers (AGPR ledger: 32+32+64 = 128).
//   * transform/ELU/epilogue byte-identical to verified round-7 forms.
// ---------------------------------------------------------------------------

#define E_EDGES       1000000
#define NTILES        31250      // E / 32
#define GRID_BLKS     512        // 256 blocks per decoder, interleaved
#define WAVES_PER_DEC 2048       // 256 blocks * 8 waves

typedef _Float16 half8  __attribute__((ext_vector_type(8)));
typedef _Float16 half4v __attribute__((ext_vector_type(4)));
typedef float    f32x4  __attribute__((ext_vector_type(4)));
typedef unsigned int uint4v __attribute__((ext_vector_type(4)));

__device__ __forceinline__ float elu_f(float x) {
    return (x > 0.f) ? x : (__expf(x) - 1.f);
}

// packed f32x2 -> f16x2 (RTZ), as a raw 32-bit word
__device__ __forceinline__ unsigned int pk16(float lo, float hi) {
    return __builtin_bit_cast(unsigned int, __builtin_amdgcn_cvt_pkrtz(lo, hi));
}

// MFMA with accumulator pinned to AGPRs. D=A*B+C, C==D (accumulate in place).
__device__ __forceinline__ void mfma_a(f32x4& acc, half8 af, half8 bf) {
    asm("v_mfma_f32_16x16x32_f16 %0, %1, %2, %0"
        : "+a"(acc)
        : "v"(af), "v"(bf));
}
// MFMA first K-step: D = A*B + C, C = persistent bias AGPR, C != D.
// "=&a" early-clobber: D guaranteed disjoint from A, B, AND C.
__device__ __forceinline__ void mfma_init(f32x4& d, half8 af, half8 bf, const f32x4& c) {
    asm("v_mfma_f32_16x16x32_f16 %0, %1, %2, %3"
        : "=&a"(d)
        : "v"(af), "v"(bf), "a"(c));
}

// Cross-lane word redistribution for C-layout -> B-fragment conversion.
//   lo[l] = (l<32 ? A0 : A1)[ ((l>>4)&1)*32 +      (l&15) ]
//   hi[l] = (l<32 ? A0 : A1)[ ((l>>4)&1)*32 + 16 + (l&15) ]
// permlane32_swap + permlane16_swap (both outputs used). Verified rounds 1-7.
__device__ __forceinline__ void xpose_pair(unsigned int A0, unsigned int A1,
                                           unsigned int& lo, unsigned int& hi) {
#if __has_builtin(__builtin_amdgcn_permlane32_swap) && __has_builtin(__builtin_amdgcn_permlane16_swap)
    auto t = __builtin_amdgcn_permlane32_swap(A0, A1, false, false);
    auto u = __builtin_amdgcn_permlane16_swap(t[0], t[1], false, false);
    lo = u[0]; hi = u[1];
#else
    const int l = (int)(threadIdx.x & 63);
    const int src = (((l >> 4) & 1) << 5) | (l & 15);
    unsigned int x0 = (unsigned int)__shfl((int)A0, src);
    unsigned int x1 = (unsigned int)__shfl((int)A1, src);
    unsigned int y0 = (unsigned int)__shfl((int)A0, src + 16);
    unsigned int y1 = (unsigned int)__shfl((int)A1, src + 16);
    lo = (l < 32) ? x0 : x1;
    hi = (l < 32) ? y0 : y1;
#endif
}

// fused f32 -> f16 conversion of both embedding tables
__global__ void cvt_tables(const float* __restrict__ u, const float* __restrict__ it,
                           _Float16* __restrict__ ou, _Float16* __restrict__ oi,
                           int n4u, int n4i) {
    int i = blockIdx.x * blockDim.x + threadIdx.x;
    const float4* src; half4v* dst; int j;
    if (i < n4u) { src = (const float4*)u; dst = (half4v*)ou; j = i; }
    else {
        j = i - n4u;
        if (j >= n4i) return;
        src = (const float4*)it; dst = (half4v*)oi;
    }
    float4 f = src[j];
    half4v h;
    h[0] = (_Float16)f.x; h[1] = (_Float16)f.y;
    h[2] = (_Float16)f.z; h[3] = (_Float16)f.w;
    dst[j] = h;
}

template<bool PRE16>
__device__ __forceinline__ void gather_tiles(
    half8 (&a)[2][8], const void* src_tab, const void* dst_tab,
    const int (&si)[2], const int (&di)[2], int g)
{
    #pragma unroll
    for (int s = 0; s < 2; ++s) {
        if constexpr (PRE16) {
            const half8* rs = (const half8*)((const _Float16*)src_tab + (size_t)si[s] * 128) + g;
            const half8* rd = (const half8*)((const _Float16*)dst_tab + (size_t)di[s] * 128) + g;
            #pragma unroll
            for (int kk = 0; kk < 4; ++kk) a[s][kk]     = rs[kk * 4];
            #pragma unroll
            for (int kk = 0; kk < 4; ++kk) a[s][4 + kk] = rd[kk * 4];
        } else {
            const float* rs = (const float*)src_tab + (size_t)si[s] * 128 + g * 8;
            const float* rd = (const float*)dst_tab + (size_t)di[s] * 128 + g * 8;
            #pragma unroll
            for (int kk = 0; kk < 8; ++kk) {
                const float* base = (kk < 4) ? (rs + kk * 32) : (rd + (kk - 4) * 32);
                float4 p0 = *(const float4*)base;
                float4 p1 = *(const float4*)(base + 4);
                half8 fr;
                fr[0] = (_Float16)p0.x; fr[1] = (_Float16)p0.y;
                fr[2] = (_Float16)p0.z; fr[3] = (_Float16)p0.w;
                fr[4] = (_Float16)p1.x; fr[5] = (_Float16)p1.y;
                fr[6] = (_Float16)p1.z; fr[7] = (_Float16)p1.w;
                a[s][kk] = fr;
            }
        }
    }
}

__device__ __forceinline__ void idx_load(const int* __restrict__ src_idx,
                                         const int* __restrict__ dst_idx,
                                         int t, int n, int (&si)[2], int (&di)[2])
{
    #pragma unroll
    for (int s = 0; s < 2; ++s) {
        const int e = t * 32 + s * 16 + n;
        si[s] = src_idx[e];
        di[s] = dst_idx[e];
    }
}

template<bool PRE16>
__global__ __launch_bounds__(512, 2) void edge_mlp(
    const void* __restrict__ tabU, const void* __restrict__ tabI,
    const int* __restrict__ ui_src, const int* __restrict__ ui_dst,
    const int* __restrict__ iu_src, const int* __restrict__ iu_dst,
    const float* __restrict__ W0_ui, const float* __restrict__ b0_ui,
    const float* __restrict__ W1_ui, const float* __restrict__ b1_ui,
    const float* __restrict__ W2_ui, const float* __restrict__ b2_ui,
    const float* __restrict__ W0_iu, const float* __restrict__ b0_iu,
    const float* __restrict__ W1_iu, const float* __restrict__ b1_iu,
    const float* __restrict__ W2_iu, const float* __restrict__ b2_iu,
    float* __restrict__ out)
{
    __shared__ __align__(16) _Float16 wlds[49152];   // 96 KiB: W0 (64) + W1 (32) frags

    const int dec = blockIdx.x & 1;
    const void* src_tab = dec ? tabI : tabU;
    const void* dst_tab = dec ? tabU : tabI;
    const int* src_idx = dec ? iu_src : ui_src;
    const int* dst_idx = dec ? iu_dst : ui_dst;
    const float* W0 = dec ? W0_iu : W0_ui;
    const float* b0 = dec ? b0_iu : b0_ui;
    const float* W1 = dec ? W1_iu : W1_ui;
    const float* b1 = dec ? b1_iu : b1_ui;
    const float* W2 = dec ? W2_iu : W2_ui;
    const float* b2 = dec ? b2_iu : b2_ui;
    float* op = out + (dec ? E_EDGES : 0);

    const int tid = threadIdx.x;
    const int l = tid & 63;        // lane
    const int w = tid >> 6;        // wave 0..7
    const int n = l & 15;
    const int g = l >> 4;          // lane quad 0..3

    // ---- preload W0^T A-frags: frag f = kk*8 + hr, 64 frags, 8 waves x 8 ----
    // frag elem (lane l, i): W0[(kk*32 + g*8 + i)*128 + hr*16 + n]
    #pragma unroll
    for (int q = 0; q < 8; ++q) {
        const int f = w * 8 + q;
        const int kk = f >> 3, hr = f & 7;
        const int kbase = kk * 32 + g * 8;
        const int col = hr * 16 + n;
        half8 fr;
        #pragma unroll
        for (int i = 0; i < 8; ++i) fr[i] = (_Float16)W0[(kbase + i) * 128 + col];
        *(half8*)&wlds[f * 512 + l * 8] = fr;
    }
    // ---- preload W1^T A-frags: 32 frags, 8 waves x 4 ----
    #pragma unroll
    for (int q = 0; q < 4; ++q) {
        const int f = w * 4 + q;
        const int kk = f >> 3, hr = f & 7;
        const int kbase = kk * 32 + g * 8;
        const int col = hr * 16 + n;
        half8 fr;
        #pragma unroll
        for (int i = 0; i < 8; ++i) fr[i] = (_Float16)W1[(kbase + i) * 128 + col];
        *(half8*)&wlds[32768 + f * 512 + l * 8] = fr;
    }

    // ---- loop-invariant per-lane constants (C row = hr*16 + g*4 + v) ----
    // b0A/b1A pinned to AGPRs; consumed only by mfma_init's "a" C operand.
    f32x4 b0A[8], b1A[8], w2r[8];
    #pragma unroll
    for (int hr = 0; hr < 8; ++hr) {
        b0A[hr] = *(const f32x4*)&b0[hr * 16 + g * 4];
        b1A[hr] = *(const f32x4*)&b1[hr * 16 + g * 4];
        w2r[hr] = *(const f32x4*)&W2[hr * 16 + g * 4];
        asm("" : "+a"(b0A[hr]));
        asm("" : "+a"(b1A[hr]));
    }
    const float b2s = b2[0];
    __syncthreads();   // only barrier; main loop is barrier-free

    const half8* w0f = (const half8*)&wlds[0];
    const half8* w1f = (const half8*)&wlds[32768];

    const int wid = (blockIdx.x >> 1) * 8 + w;     // 0..2047 within decoder

    // ================= software-pipelined main loop =================
    int tc = wid;                                  // current tile (always valid)
    int si[2], di[2];
    idx_load(src_idx, dst_idx, tc, n, si, di);
    half8 a[2][8];
    gather_tiles<PRE16>(a, src_tab, dst_tab, si, di, g);
    int tn = tc + WAVES_PER_DEC;                   // next tile (maybe invalid)
    idx_load(src_idx, dst_idx, (tn < NTILES) ? tn : tc, n, si, di);

    while (true) {
        // ---- layer 0: acc[s][hr] = W0^T @ X^T, bias via C-operand (kk=0) ----
        f32x4 acc[2][8];
        #pragma unroll
        for (int hr = 0; hr < 8; ++hr) {
            const half8 wf = w0f[hr * 64 + l];     // kk = 0
            mfma_init(acc[0][hr], wf, a[0][0], b0A[hr]);
            mfma_init(acc[1][hr], wf, a[1][0], b0A[hr]);
        }
        #pragma unroll
        for (int kk = 1; kk < 8; ++kk) {
            #pragma unroll
            for (int hr = 0; hr < 8; ++hr) {
                const half8 wf = w0f[(kk * 8 + hr) * 64 + l];
                mfma_a(acc[0][hr], wf, a[0][kk]);
                mfma_a(acc[1][hr], wf, a[1][kk]);
            }
        }

        // pin the prefetch below the MFMAs (a[] regs now dead -> reuse, no spill)
        __builtin_amdgcn_sched_barrier(0);

        // ---- prefetch next tile's gathers into a[] (latency hidden below) ----
        gather_tiles<PRE16>(a, src_tab, dst_tab, si, di, g);
        // ---- prefetch idx for the tile after next ----
        {
            const int tnc = (tn < NTILES) ? tn : tc;
            const int t2 = tn + WAVES_PER_DEC;
            const int t2c = (t2 < NTILES) ? t2 : tnc;
            idx_load(src_idx, dst_idx, t2c, n, si, di);
        }

        // ---- ELU + cvt_pkrtz + permlane: C-layout -> layer-1 B-frags ----
        // (verbatim round-7 verified form; bias already in acc via C-init)
        unsigned int v01[2][8], v23[2][8];
        #pragma unroll
        for (int hr = 0; hr < 8; ++hr) {
            #pragma unroll
            for (int s = 0; s < 2; ++s) {
                v01[s][hr] = pk16(elu_f(acc[s][hr][0]), elu_f(acc[s][hr][1]));
                v23[s][hr] = pk16(elu_f(acc[s][hr][2]), elu_f(acc[s][hr][3]));
            }
        }
        half8 bfr[2][4];
        #pragma unroll
        for (int s = 0; s < 2; ++s) {
            #pragma unroll
            for (int kk = 0; kk < 4; ++kk) {
                unsigned int w0lo, w0hi, w1lo, w1hi;
                xpose_pair(v01[s][2 * kk], v01[s][2 * kk + 1], w0lo, w0hi);
                xpose_pair(v23[s][2 * kk], v23[s][2 * kk + 1], w1lo, w1hi);
                uint4v wd;
                wd.x = w0lo;   // elems i0,i1 (v=0,1 from groups {0,2})
                wd.y = w1lo;   // elems i2,i3 (v=2,3 from groups {0,2})
                wd.z = w0hi;   // elems i4,i5 (v=0,1 from groups {1,3})
                wd.w = w1hi;   // elems i6,i7 (v=2,3 from groups {1,3})
                bfr[s][kk] = __builtin_bit_cast(half8, wd);
            }
        }

        // ---- layer 1: acc[s][hr] = W1^T @ H0^T, bias via C-operand (kk=0) ----
        // (acc reused -- layer-0 values fully consumed by the transform above)
        #pragma unroll
        for (int hr = 0; hr < 8; ++hr) {
            const half8 wf = w1f[hr * 64 + l];     // kk = 0
            mfma_init(acc[0][hr], wf, bfr[0][0], b1A[hr]);
            mfma_init(acc[1][hr], wf, bfr[1][0], b1A[hr]);
        }
        #pragma unroll
        for (int kk = 1; kk < 4; ++kk) {
            #pragma unroll
            for (int hr = 0; hr < 8; ++hr) {
                const half8 wf = w1f[(kk * 8 + hr) * 64 + l];
                mfma_a(acc[0][hr], wf, bfr[0][kk]);
                mfma_a(acc[1][hr], wf, bfr[1][kk]);
            }
        }

        // ---- layer 2: per-lane 32-ch ELU+dot, reduce across lane quads ----
        // (verbatim round-7 verified form)
        float accs0 = 0.f, accs1 = 0.f;
        #pragma unroll
        for (int hr = 0; hr < 8; ++hr) {
            #pragma unroll
            for (int v = 0; v < 4; ++v) {
                accs0 += elu_f(acc[0][hr][v]) * w2r[hr][v];
                accs1 += elu_f(acc[1][hr][v]) * w2r[hr][v];
            }
        }
        accs0 += __shfl_xor(accs0, 16); accs0 += __shfl_xor(accs0, 32);
        accs1 += __shfl_xor(accs1, 16); accs1 += __shfl_xor(accs1, 32);
        // lane l (<32) -> edge e0 + l; set = bit4 of l
        if (l < 32) {
            const float sel = (l & 16) ? accs1 : accs0;
            op[tc * 32 + l] = 1.f / (1.f + __expf(-(sel + b2s)));
        }

        if (tn >= NTILES) break;
        tc = tn;
        tn = tc + WAVES_PER_DEC;
    }
}

extern "C" void kernel_launch(void* const* d_in, const int* in_sizes, int n_in,
                              void* d_out, int out_size, void* d_ws, size_t ws_size,
                              hipStream_t stream) {
    const float* user_emb = (const float*)d_in[0];
    const float* item_emb = (const float*)d_in[1];
    const int* ui_src = (const int*)d_in[2];
    const int* ui_dst = (const int*)d_in[3];
    const int* iu_src = (const int*)d_in[4];
    const int* iu_dst = (const int*)d_in[5];
    const float* W0_ui = (const float*)d_in[6];
    const float* b0_ui = (const float*)d_in[7];
    const float* W1_ui = (const float*)d_in[8];
    const float* b1_ui = (const float*)d_in[9];
    const float* W2_ui = (const float*)d_in[10];
    const float* b2_ui = (const float*)d_in[11];
    const float* W0_iu = (const float*)d_in[12];
    const float* b0_iu = (const float*)d_in[13];
    const float* W1_iu = (const float*)d_in[14];
    const float* b1_iu = (const float*)d_in[15];
    const float* W2_iu = (const float*)d_in[16];
    const float* b2_iu = (const float*)d_in[17];
    float* out = (float*)d_out;

    const size_t nuser = (size_t)100000 * 128;
    const size_t nitem = (size_t)50000 * 128;
    const size_t need = (nuser + nitem) * sizeof(unsigned short);

    if (ws_size >= need) {
        _Float16* u16 = (_Float16*)d_ws;
        _Float16* i16 = u16 + nuser;
        const int n4u = (int)(nuser / 4);
        const int n4i = (int)(nitem / 4);
        cvt_tables<<<dim3((unsigned)((n4u + n4i + 255) / 256)), dim3(256), 0, stream>>>(
            user_emb, item_emb, u16, i16, n4u, n4i);
        edge_mlp<true><<<dim3(GRID_BLKS), dim3(512), 0, stream>>>(
            (const void*)u16, (const void*)i16,
            ui_src, ui_dst, iu_src, iu_dst,
            W0_ui, b0_ui, W1_ui, b1_ui, W2_ui, b2_ui,
            W0_iu, b0_iu, W1_iu, b1_iu, W2_iu, b2_iu, out);
    } else {
        edge_mlp<false><<<dim3(GRID_BLKS), dim3(512), 0, stream>>>(
            (const void*)user_emb, (const void*)item_emb,
            ui_src, ui_dst, iu_src, iu_dst,
            W0_ui, b0_ui, W1_ui, b1_ui, W2_ui, b2_ui,
            W0_iu, b0_iu, W1_iu, b1_iu, W2_iu, b2_iu, out);
    }
}